// Round 2
// baseline (1304.502 us; speedup 1.0000x reference)
//
#include <hip/hip_runtime.h>

#define DIM    1024
#define NHEADS 16
#define HDIM   64
#define BB     2
#define SS     2048
#define MTOT   (BB * SS)  // 4096

// ---------------------------------------------------------------------------
// QKV GEMM: C[m,n] = sum_k x[m,k]*w[k,n] + bias[n], scattered to q/k/v [B,H,S,h]
// 128x64 tile, BK=16, 256 threads, 8x4 micro-tile.
// As stored K-major with stride 132 (bank-conflict-free transpose write/read).
// ---------------------------------------------------------------------------
__global__ __launch_bounds__(256) void qkv_gemm_kernel(
    const float* __restrict__ x, const float* __restrict__ w,
    const float* __restrict__ bias,
    float* __restrict__ qb, float* __restrict__ kbuf, float* __restrict__ vbuf) {
  __shared__ float As[16][132];
  __shared__ float Bs[16][64];
  const int tid  = threadIdx.x;
  const int row0 = blockIdx.x * 128;
  const int col0 = blockIdx.y * 64;
  const int tr = tid >> 4, tc = tid & 15;        // 16x16 thread grid
  const int am = tid >> 2, ak = (tid & 3) << 2;  // A-tile load coords
  const int bk = tid >> 4, bn = (tid & 15) << 2; // B-tile load coords

  float acc[8][4];
#pragma unroll
  for (int i = 0; i < 8; ++i)
#pragma unroll
    for (int j = 0; j < 4; ++j) acc[i][j] = 0.f;

  for (int k0 = 0; k0 < DIM; k0 += 16) {
    const float4 av0 = *(const float4*)&x[(size_t)(row0 + am) * DIM + k0 + ak];
    const float4 av1 = *(const float4*)&x[(size_t)(row0 + am + 64) * DIM + k0 + ak];
    const float4 bv  = *(const float4*)&w[(size_t)(k0 + bk) * (3 * DIM) + col0 + bn];
    __syncthreads();  // previous iteration's LDS readers done
    As[ak + 0][am] = av0.x; As[ak + 1][am] = av0.y;
    As[ak + 2][am] = av0.z; As[ak + 3][am] = av0.w;
    As[ak + 0][am + 64] = av1.x; As[ak + 1][am + 64] = av1.y;
    As[ak + 2][am + 64] = av1.z; As[ak + 3][am + 64] = av1.w;
    *(float4*)&Bs[bk][bn] = bv;
    __syncthreads();
#pragma unroll
    for (int kk = 0; kk < 16; ++kk) {
      float ar[8], br[4];
      *(float4*)&ar[0] = *(const float4*)&As[kk][tr * 8];
      *(float4*)&ar[4] = *(const float4*)&As[kk][tr * 8 + 4];
      *(float4*)&br[0] = *(const float4*)&Bs[kk][tc * 4];
#pragma unroll
      for (int i = 0; i < 8; ++i)
#pragma unroll
        for (int j = 0; j < 4; ++j) acc[i][j] += ar[i] * br[j];
    }
  }
  // epilogue: scatter to q/k/v in [B,H,S,h]; block covers one 64-col band
  const int which = col0 >> 10;            // 0=q 1=k 2=v
  const int head  = (col0 & 1023) >> 6;
  const int hh    = tc << 2;               // col0 % 64 == 0
  float* __restrict__ dst = (which == 0) ? qb : (which == 1 ? kbuf : vbuf);
  float bias_r[4];
  *(float4*)&bias_r[0] = *(const float4*)&bias[col0 + (tc << 2)];
#pragma unroll
  for (int i = 0; i < 8; ++i) {
    const int mrow  = row0 + tr * 8 + i;
    const int b_idx = mrow >> 11, s_idx = mrow & 2047;
    float4 o;
    o.x = acc[i][0] + bias_r[0]; o.y = acc[i][1] + bias_r[1];
    o.z = acc[i][2] + bias_r[2]; o.w = acc[i][3] + bias_r[3];
    *(float4*)&dst[((size_t)(b_idx * NHEADS + head) * SS + s_idx) * HDIM + hh] = o;
  }
}

// ---------------------------------------------------------------------------
// Proj GEMM: out[m,n] = sum_k a[m,k]*w[k,n] + bias[n]   (N = 1024)
// ---------------------------------------------------------------------------
__global__ __launch_bounds__(256) void proj_gemm_kernel(
    const float* __restrict__ a, const float* __restrict__ w,
    const float* __restrict__ bias, float* __restrict__ out) {
  __shared__ float As[16][132];
  __shared__ float Bs[16][64];
  const int tid  = threadIdx.x;
  const int row0 = blockIdx.x * 128;
  const int col0 = blockIdx.y * 64;
  const int tr = tid >> 4, tc = tid & 15;
  const int am = tid >> 2, ak = (tid & 3) << 2;
  const int bk = tid >> 4, bn = (tid & 15) << 2;

  float acc[8][4];
#pragma unroll
  for (int i = 0; i < 8; ++i)
#pragma unroll
    for (int j = 0; j < 4; ++j) acc[i][j] = 0.f;

  for (int k0 = 0; k0 < DIM; k0 += 16) {
    const float4 av0 = *(const float4*)&a[(size_t)(row0 + am) * DIM + k0 + ak];
    const float4 av1 = *(const float4*)&a[(size_t)(row0 + am + 64) * DIM + k0 + ak];
    const float4 bv  = *(const float4*)&w[(size_t)(k0 + bk) * DIM + col0 + bn];
    __syncthreads();
    As[ak + 0][am] = av0.x; As[ak + 1][am] = av0.y;
    As[ak + 2][am] = av0.z; As[ak + 3][am] = av0.w;
    As[ak + 0][am + 64] = av1.x; As[ak + 1][am + 64] = av1.y;
    As[ak + 2][am + 64] = av1.z; As[ak + 3][am + 64] = av1.w;
    *(float4*)&Bs[bk][bn] = bv;
    __syncthreads();
#pragma unroll
    for (int kk = 0; kk < 16; ++kk) {
      float ar[8], br[4];
      *(float4*)&ar[0] = *(const float4*)&As[kk][tr * 8];
      *(float4*)&ar[4] = *(const float4*)&As[kk][tr * 8 + 4];
      *(float4*)&br[0] = *(const float4*)&Bs[kk][tc * 4];
#pragma unroll
      for (int i = 0; i < 8; ++i)
#pragma unroll
        for (int j = 0; j < 4; ++j) acc[i][j] += ar[i] * br[j];
    }
  }
  float bias_r[4];
  *(float4*)&bias_r[0] = *(const float4*)&bias[col0 + (tc << 2)];
#pragma unroll
  for (int i = 0; i < 8; ++i) {
    const int mrow = row0 + tr * 8 + i;
    float4 o;
    o.x = acc[i][0] + bias_r[0]; o.y = acc[i][1] + bias_r[1];
    o.z = acc[i][2] + bias_r[2]; o.w = acc[i][3] + bias_r[3];
    *(float4*)&out[(size_t)mrow * DIM + col0 + (tc << 2)] = o;
  }
}

// ---------------------------------------------------------------------------
// Flash attention fp32. Block = (qt, b*H+head), 256 threads, QB=64, KB=64.
// Thread (r = tid>>2, q4 = tid&3) owns out row r, cols [16*q4, 16*q4+16).
// K staged transposed Kt[kk][key] (stride 68); P reuses the Kt buffer.
// Scale 1/8 folded into Q at LDS store. Online softmax (m,l per row,
// replicated across the 4 quad lanes via __shfl_xor).
// ---------------------------------------------------------------------------
__global__ __launch_bounds__(256) void attn_kernel(
    const float* __restrict__ qb, const float* __restrict__ kbuf,
    const float* __restrict__ vbuf, float* __restrict__ ao) {
  __shared__ float Qs[64 * 68];
  __shared__ float KtPs[64 * 68];
  __shared__ float Vs[64 * 64];
  const int tid  = threadIdx.x;
  const int qt   = blockIdx.x;   // 0..31
  const int bh   = blockIdx.y;   // 0..31
  const int b    = bh >> 4, head = bh & 15;
  const float* __restrict__ qsrc  = qb   + ((size_t)bh * SS + qt * 64) * HDIM;
  const float* __restrict__ kbase = kbuf + (size_t)bh * SS * HDIM;
  const float* __restrict__ vbase = vbuf + (size_t)bh * SS * HDIM;
  const int r   = tid >> 2;
  const int q4  = tid & 3;
  const int hh0 = q4 << 4;

#pragma unroll
  for (int it = 0; it < 4; ++it) {
    const int fi = tid + it * 256;             // float4 index into 64x64 tile
    const int row = fi >> 4, c4 = (fi & 15) << 2;
    float4 qv = *(const float4*)&qsrc[row * HDIM + c4];
    qv.x *= 0.125f; qv.y *= 0.125f; qv.z *= 0.125f; qv.w *= 0.125f;
    *(float4*)&Qs[row * 68 + c4] = qv;
  }

  float mrun = -1e30f, lrun = 0.f;
  float acc[16];
#pragma unroll
  for (int j = 0; j < 16; ++j) acc[j] = 0.f;

  for (int kt = 0; kt < SS / 64; ++kt) {
    const float* __restrict__ ksrc = kbase + (size_t)kt * 64 * HDIM;
    const float* __restrict__ vsrc = vbase + (size_t)kt * 64 * HDIM;
    float4 kreg[4], vreg[4];
#pragma unroll
    for (int it = 0; it < 4; ++it) {
      const int fi = tid + it * 256;
      kreg[it] = *(const float4*)&ksrc[(fi >> 4) * HDIM + ((fi & 15) << 2)];
      vreg[it] = *(const float4*)&vsrc[(fi >> 4) * HDIM + ((fi & 15) << 2)];
    }
    __syncthreads();   // previous iteration's PV readers done
#pragma unroll
    for (int it = 0; it < 4; ++it) {
      const int fi = tid + it * 256;
      const int key = fi >> 4, c4 = (fi & 15) << 2;
      *(float4*)&Vs[key * HDIM + c4] = vreg[it];
      KtPs[(c4 + 0) * 68 + key] = kreg[it].x;  // transpose: Kt[kk][key]
      KtPs[(c4 + 1) * 68 + key] = kreg[it].y;
      KtPs[(c4 + 2) * 68 + key] = kreg[it].z;
      KtPs[(c4 + 3) * 68 + key] = kreg[it].w;
    }
    __syncthreads();

    // scores: s[j] = (1/8) * Q[r,:] . K[16*q4+j,:]
    float s[16];
#pragma unroll
    for (int j = 0; j < 16; ++j) s[j] = 0.f;
#pragma unroll 4
    for (int kk = 0; kk < 64; ++kk) {
      const float qv = Qs[r * 68 + kk];
      float kv[16];
      const float* __restrict__ kp = &KtPs[kk * 68 + hh0];
      *(float4*)&kv[0]  = *(const float4*)&kp[0];
      *(float4*)&kv[4]  = *(const float4*)&kp[4];
      *(float4*)&kv[8]  = *(const float4*)&kp[8];
      *(float4*)&kv[12] = *(const float4*)&kp[12];
#pragma unroll
      for (int j = 0; j < 16; ++j) s[j] += qv * kv[j];
    }

    // online softmax (row stats replicated across quad)
    float tmax = s[0];
#pragma unroll
    for (int j = 1; j < 16; ++j) tmax = fmaxf(tmax, s[j]);
    tmax = fmaxf(tmax, __shfl_xor(tmax, 1));
    tmax = fmaxf(tmax, __shfl_xor(tmax, 2));
    const float mnew = fmaxf(mrun, tmax);
    const float f = __expf(mrun - mnew);
    float p[16], rsum = 0.f;
#pragma unroll
    for (int j = 0; j < 16; ++j) { p[j] = __expf(s[j] - mnew); rsum += p[j]; }
    rsum += __shfl_xor(rsum, 1);
    rsum += __shfl_xor(rsum, 2);
    lrun = lrun * f + rsum;
    mrun = mnew;
#pragma unroll
    for (int j = 0; j < 16; ++j) acc[j] *= f;

    __syncthreads();   // all score-readers of Kt done before P overwrites it
#pragma unroll
    for (int j = 0; j < 16; ++j) KtPs[r * 68 + hh0 + j] = p[j];
    __syncthreads();

    // PV: acc[j] += sum_c P[r][c] * V[c][hh0+j]
#pragma unroll 4
    for (int c = 0; c < 64; ++c) {
      const float pb = KtPs[r * 68 + c];
      float vv[16];
      const float* __restrict__ vp = &Vs[c * HDIM + hh0];
      *(float4*)&vv[0]  = *(const float4*)&vp[0];
      *(float4*)&vv[4]  = *(const float4*)&vp[4];
      *(float4*)&vv[8]  = *(const float4*)&vp[8];
      *(float4*)&vv[12] = *(const float4*)&vp[12];
#pragma unroll
      for (int j = 0; j < 16; ++j) acc[j] += pb * vv[j];
    }
  }

  const float inv_l = 1.f / lrun;
  float* __restrict__ dst =
      ao + ((size_t)(b * SS + qt * 64 + r) * DIM) + head * HDIM + hh0;
#pragma unroll
  for (int jv = 0; jv < 4; ++jv) {
    float4 o;
    o.x = acc[jv * 4 + 0] * inv_l; o.y = acc[jv * 4 + 1] * inv_l;
    o.z = acc[jv * 4 + 2] * inv_l; o.w = acc[jv * 4 + 3] * inv_l;
    *(float4*)&dst[jv * 4] = o;
  }
}

// ---------------------------------------------------------------------------
extern "C" void kernel_launch(void* const* d_in, const int* in_sizes, int n_in,
                              void* d_out, int out_size, void* d_ws, size_t ws_size,
                              hipStream_t stream) {
  const float* x      = (const float*)d_in[0];
  const float* w_qkv  = (const float*)d_in[1];
  const float* b_qkv  = (const float*)d_in[2];
  const float* w_proj = (const float*)d_in[3];
  const float* b_proj = (const float*)d_in[4];
  float* out = (float*)d_out;

  float* qb   = (float*)d_ws;                       // [B,H,S,h] 16 MB
  float* kbuf = qb   + (size_t)MTOT * DIM;          // 16 MB
  float* vbuf = kbuf + (size_t)MTOT * DIM;          // 16 MB
  float* ao   = vbuf + (size_t)MTOT * DIM;          // [B,S,D]  16 MB

  qkv_gemm_kernel<<<dim3(32, 48), 256, 0, stream>>>(x, w_qkv, b_qkv, qb, kbuf, vbuf);
  attn_kernel<<<dim3(32, 32), 256, 0, stream>>>(qb, kbuf, vbuf, ao);
  proj_gemm_kernel<<<dim3(32, 16), 256, 0, stream>>>(ao, w_proj, b_proj, out);
}

// Round 3
// 286.839 us; speedup vs baseline: 4.5479x; 4.5479x over previous
//
#include <hip/hip_runtime.h>
#include <hip/hip_bf16.h>

#define DIM    1024
#define NHEADS 16
#define HDIM   64
#define BB     2
#define SS     2048
#define MTOT   (BB * SS)  // 4096

typedef unsigned short u16;
typedef __attribute__((ext_vector_type(8))) short short8;   // 8 bf16 = 4 VGPR (MFMA A/B frag)
typedef __attribute__((ext_vector_type(4))) float f32x4;    // MFMA C/D frag

__device__ inline u16 f2b(float f) {
  __hip_bfloat16 h = __float2bfloat16(f);
  return *reinterpret_cast<u16*>(&h);
}
__device__ inline f32x4 zero4() { f32x4 v = {0.f, 0.f, 0.f, 0.f}; return v; }

// async global->LDS, 16B per lane; LDS dest = wave-uniform base + lane*16
#define GLD_LDS16(GP, LP)                                                   \
  __builtin_amdgcn_global_load_lds(                                         \
      (const __attribute__((address_space(1))) unsigned int*)               \
          (unsigned long long)(const void*)(GP),                            \
      (__attribute__((address_space(3))) unsigned int*)                     \
          (unsigned int)(unsigned long long)(const void*)(LP),              \
      16, 0, 0)

// ---------------------------------------------------------------------------
// cast fp32 -> bf16, 8 elems/thread
// ---------------------------------------------------------------------------
__global__ __launch_bounds__(256) void cast_bf16_kernel(
    const float* __restrict__ in, u16* __restrict__ out, int n8) {
  const int i = blockIdx.x * blockDim.x + threadIdx.x;
  if (i >= n8) return;
  const float4 a = ((const float4*)in)[i * 2];
  const float4 b = ((const float4*)in)[i * 2 + 1];
  union { u16 u[8]; uint4 v; } r;
  r.u[0] = f2b(a.x); r.u[1] = f2b(a.y); r.u[2] = f2b(a.z); r.u[3] = f2b(a.w);
  r.u[4] = f2b(b.x); r.u[5] = f2b(b.y); r.u[6] = f2b(b.z); r.u[7] = f2b(b.w);
  ((uint4*)out)[i] = r.v;
}

// ---------------------------------------------------------------------------
// transpose+cast: in [K][N] fp32 -> out [N][K] bf16, 32x32 tiles
// ---------------------------------------------------------------------------
__global__ __launch_bounds__(256) void transpose_cast_kernel(
    const float* __restrict__ in, u16* __restrict__ out, int K, int N) {
  __shared__ u16 tile[32][36];
  const int t   = threadIdx.x;
  const int n0  = blockIdx.x * 32, k0 = blockIdx.y * 32;
  const int tr  = t >> 3, tc4 = (t & 7) * 4;
  const float4 a = *(const float4*)&in[(size_t)(k0 + tr) * N + n0 + tc4];
  tile[tr][tc4 + 0] = f2b(a.x); tile[tr][tc4 + 1] = f2b(a.y);
  tile[tr][tc4 + 2] = f2b(a.z); tile[tr][tc4 + 3] = f2b(a.w);
  __syncthreads();
  union { u16 u[4]; uint2 v; } pk;
  pk.u[0] = tile[tc4 + 0][tr]; pk.u[1] = tile[tc4 + 1][tr];
  pk.u[2] = tile[tc4 + 2][tr]; pk.u[3] = tile[tc4 + 3][tr];
  *(uint2*)&out[(size_t)(n0 + tr) * K + k0 + tc4] = pk.v;
}

// ---------------------------------------------------------------------------
// V transpose (bf16): v [bh][S][64] -> vt [bh][64][S], 64x64 tiles
// ---------------------------------------------------------------------------
__global__ __launch_bounds__(256) void vtrans_kernel(
    const u16* __restrict__ v, u16* __restrict__ vt) {
  __shared__ __align__(16) u16 tile[64][72];
  const int t  = threadIdx.x;
  const int s0 = blockIdx.x * 64, bh = blockIdx.y;
#pragma unroll
  for (int it = 0; it < 2; ++it) {
    const int ci = t + it * 256;
    const int sr = ci >> 3, c8 = (ci & 7) * 8;
    *(uint4*)&tile[sr][c8] =
        *(const uint4*)&v[((size_t)(bh * SS + s0 + sr)) * 64 + c8];
  }
  __syncthreads();
#pragma unroll
  for (int it = 0; it < 2; ++it) {
    const int ci = t + it * 256;
    const int h = ci >> 3, sc = (ci & 7) * 8;
    union { u16 u[8]; uint4 q; } pk;
#pragma unroll
    for (int j = 0; j < 8; ++j) pk.u[j] = tile[sc + j][h];
    *(uint4*)&vt[((size_t)(bh * 64 + h)) * SS + s0 + sc] = pk.q;
  }
}

// ---------------------------------------------------------------------------
// QKV GEMM bf16 MFMA: xa [4096][1024] x wt [3072][1024](=w^T) + bias
//  -> q/k/v [bh][S][64] bf16; q pre-scaled by 0.125 (exact in bf16 path).
// 128x128 tile, BK=64, 4 waves (2x2), each 64x64 (4x4 frags of 16x16x32).
// ---------------------------------------------------------------------------
__global__ __launch_bounds__(256) void gemm_qkv_bf16(
    const u16* __restrict__ xa, const u16* __restrict__ wt,
    const float* __restrict__ bias,
    u16* __restrict__ qbuf, u16* __restrict__ kbuf, u16* __restrict__ vbuf) {
  __shared__ __align__(16) u16 As[128 * 64];
  __shared__ __align__(16) u16 Bs[128 * 64];
  const int tid = threadIdx.x, w = tid >> 6, lane = tid & 63;
  const int l15 = lane & 15, l4 = lane >> 4;
  const int m0 = blockIdx.x * 128, n0 = blockIdx.y * 128;
  const int wm = (w >> 1) * 64, wn = (w & 1) * 64;

  f32x4 acc[4][4];
#pragma unroll
  for (int i = 0; i < 4; ++i)
#pragma unroll
    for (int j = 0; j < 4; ++j) acc[i][j] = zero4();

  for (int k0 = 0; k0 < DIM; k0 += 64) {
#pragma unroll
    for (int j = 0; j < 4; ++j) {
      const int rowX = (w * 4 + j) * 8 + (lane >> 3);
      const int kcol = k0 + (lane & 7) * 8;
      GLD_LDS16(&xa[(size_t)(m0 + rowX) * DIM + kcol], &As[(w * 4 + j) * 512]);
      GLD_LDS16(&wt[(size_t)(n0 + rowX) * DIM + kcol], &Bs[(w * 4 + j) * 512]);
    }
    asm volatile("s_waitcnt vmcnt(0)" ::: "memory");
    __syncthreads();
#pragma unroll
    for (int kc = 0; kc < 2; ++kc) {
      short8 af[4], bfr[4];
#pragma unroll
      for (int mb = 0; mb < 4; ++mb)
        af[mb] = *(const short8*)&As[(wm + mb * 16 + l15) * 64 + kc * 32 + l4 * 8];
#pragma unroll
      for (int nb = 0; nb < 4; ++nb)
        bfr[nb] = *(const short8*)&Bs[(wn + nb * 16 + l15) * 64 + kc * 32 + l4 * 8];
#pragma unroll
      for (int mb = 0; mb < 4; ++mb)
#pragma unroll
        for (int nb = 0; nb < 4; ++nb)
          acc[mb][nb] = __builtin_amdgcn_mfma_f32_16x16x32_bf16(
              af[mb], bfr[nb], acc[mb][nb], 0, 0, 0);
    }
    __syncthreads();
  }

  // epilogue: wave's 64-col band lies in exactly one head & one of q/k/v
  const int colb  = n0 + wn;
  const int which = colb >> 10;
  const int head  = (colb >> 6) & 15;
  u16* __restrict__ dst = (which == 0) ? qbuf : (which == 1 ? kbuf : vbuf);
  const float scale = (which == 0) ? 0.125f : 1.0f;
#pragma unroll
  for (int nb = 0; nb < 4; ++nb) {
    const int col = colb + nb * 16 + l15;
    const float bv = bias[col];
    const int h = col & 63;
#pragma unroll
    for (int mb = 0; mb < 4; ++mb)
#pragma unroll
      for (int r = 0; r < 4; ++r) {
        const int row = m0 + wm + mb * 16 + l4 * 4 + r;
        const int b = row >> 11, s = row & 2047;
        dst[((size_t)((b * NHEADS + head) * SS + s)) * 64 + h] =
            f2b((acc[mb][nb][r] + bv) * scale);
      }
  }
}

// ---------------------------------------------------------------------------
// Flash attention bf16 MFMA. Block=(qt 0..31, bh 0..31), 4 waves x 16 q-rows.
// KB=64. K/Vt staged in LDS with XOR chunk swizzle (c ^= row&7, 16B chunks).
// P goes through wave-private swizzled LDS for the A-operand relayout.
// ---------------------------------------------------------------------------
__global__ __launch_bounds__(256) void attn_mfma(
    const u16* __restrict__ qbuf, const u16* __restrict__ kbuf,
    const u16* __restrict__ vtbuf, u16* __restrict__ aobuf) {
  __shared__ __align__(16) u16 Ks[64 * 64];
  __shared__ __align__(16) u16 Vs[64 * 64];
  __shared__ __align__(16) u16 Ps[4 * 16 * 64];
  const int tid = threadIdx.x, w = tid >> 6, lane = tid & 63;
  const int l15 = lane & 15, l4 = lane >> 4;
  const int qt = blockIdx.x, bh = blockIdx.y;
  const int b = bh >> 4, head = bh & 15;

  const u16* __restrict__ qsrc  = qbuf + ((size_t)(bh * SS + qt * 64 + w * 16)) * 64;
  const u16* __restrict__ kbase = kbuf + (size_t)bh * SS * 64;
  const u16* __restrict__ vtb   = vtbuf + (size_t)bh * 64 * SS;
  u16* __restrict__ Pw = &Ps[w * 1024];

  short8 qf[2];
#pragma unroll
  for (int kc = 0; kc < 2; ++kc)
    qf[kc] = *(const short8*)&qsrc[l15 * 64 + kc * 32 + l4 * 8];

  f32x4 acco[4];
  float mrun[4], lrun[4];
#pragma unroll
  for (int i = 0; i < 4; ++i) { acco[i] = zero4(); mrun[i] = -1e30f; lrun[i] = 0.f; }

  for (int kt = 0; kt < SS / 64; ++kt) {
    __syncthreads();  // prior tile's readers done
#pragma unroll
    for (int it = 0; it < 2; ++it) {
      const int ci = tid + it * 256;
      const int row = ci >> 3, c8 = ci & 7;
      const int sw = (c8 ^ (row & 7)) * 8;
      *(uint4*)&Ks[row * 64 + sw] =
          *(const uint4*)&kbase[((size_t)(kt * 64 + row)) * 64 + c8 * 8];
      *(uint4*)&Vs[row * 64 + sw] =
          *(const uint4*)&vtb[(size_t)row * SS + kt * 64 + c8 * 8];
    }
    __syncthreads();

    // QK^T: sc[nb] rows=q (l4*4+r), cols=key (nb*16+l15)
    f32x4 sc[4];
#pragma unroll
    for (int i = 0; i < 4; ++i) sc[i] = zero4();
#pragma unroll
    for (int kc = 0; kc < 2; ++kc)
#pragma unroll
      for (int nb = 0; nb < 4; ++nb) {
        const int key = nb * 16 + l15;
        const int cc = (kc * 4 + l4) ^ (key & 7);
        const short8 kf = *(const short8*)&Ks[key * 64 + cc * 8];
        sc[nb] = __builtin_amdgcn_mfma_f32_16x16x32_bf16(qf[kc], kf, sc[nb], 0, 0, 0);
      }

    // online softmax; row stats replicated over 16-lane groups
    float tmax[4];
#pragma unroll
    for (int r = 0; r < 4; ++r) {
      tmax[r] = fmaxf(fmaxf(sc[0][r], sc[1][r]), fmaxf(sc[2][r], sc[3][r]));
      tmax[r] = fmaxf(tmax[r], __shfl_xor(tmax[r], 1));
      tmax[r] = fmaxf(tmax[r], __shfl_xor(tmax[r], 2));
      tmax[r] = fmaxf(tmax[r], __shfl_xor(tmax[r], 4));
      tmax[r] = fmaxf(tmax[r], __shfl_xor(tmax[r], 8));
    }
    float p[4][4];
#pragma unroll
    for (int r = 0; r < 4; ++r) {
      const float mnew = fmaxf(mrun[r], tmax[r]);
      const float f = __expf(mrun[r] - mnew);
      float rs = 0.f;
#pragma unroll
      for (int nb = 0; nb < 4; ++nb) {
        p[nb][r] = __expf(sc[nb][r] - mnew);
        rs += p[nb][r];
      }
      rs += __shfl_xor(rs, 1);
      rs += __shfl_xor(rs, 2);
      rs += __shfl_xor(rs, 4);
      rs += __shfl_xor(rs, 8);
      lrun[r] = lrun[r] * f + rs;
      mrun[r] = mnew;
#pragma unroll
      for (int nb = 0; nb < 4; ++nb) acco[nb][r] *= f;
    }

    // P -> wave-private LDS (bf16, swizzled rows)
#pragma unroll
    for (int nb = 0; nb < 4; ++nb)
#pragma unroll
      for (int r = 0; r < 4; ++r) {
        const int row = l4 * 4 + r, col = nb * 16 + l15;
        const int cc = (col >> 3) ^ (row & 7);
        Pw[row * 64 + cc * 8 + (col & 7)] = f2b(p[nb][r]);
      }

    // PV: acco[nb] (rows=q, cols=h)
#pragma unroll
    for (int kc = 0; kc < 2; ++kc) {
      const int ccp = (kc * 4 + l4) ^ (l15 & 7);
      const short8 pa = *(const short8*)&Pw[l15 * 64 + ccp * 8];
#pragma unroll
      for (int nb = 0; nb < 4; ++nb) {
        const int h = nb * 16 + l15;
        const int cv = (kc * 4 + l4) ^ (h & 7);
        const short8 vf = *(const short8*)&Vs[h * 64 + cv * 8];
        acco[nb] = __builtin_amdgcn_mfma_f32_16x16x32_bf16(pa, vf, acco[nb], 0, 0, 0);
      }
    }
  }

  // epilogue -> ao [4096][1024] bf16 (proj A-operand layout)
#pragma unroll
  for (int nb = 0; nb < 4; ++nb)
#pragma unroll
    for (int r = 0; r < 4; ++r) {
      const int s = qt * 64 + w * 16 + l4 * 4 + r;
      const float o = acco[nb][r] / lrun[r];
      aobuf[((size_t)(b * SS + s)) * DIM + head * 64 + nb * 16 + l15] = f2b(o);
    }
}

// ---------------------------------------------------------------------------
// Proj GEMM bf16 MFMA: ao [4096][1024] x wpt [1024][1024](=w^T) + bias -> fp32
// ---------------------------------------------------------------------------
__global__ __launch_bounds__(256) void gemm_proj_bf16(
    const u16* __restrict__ ao, const u16* __restrict__ wpt,
    const float* __restrict__ bias, float* __restrict__ out) {
  __shared__ __align__(16) u16 As[128 * 64];
  __shared__ __align__(16) u16 Bs[128 * 64];
  const int tid = threadIdx.x, w = tid >> 6, lane = tid & 63;
  const int l15 = lane & 15, l4 = lane >> 4;
  const int m0 = blockIdx.x * 128, n0 = blockIdx.y * 128;
  const int wm = (w >> 1) * 64, wn = (w & 1) * 64;

  f32x4 acc[4][4];
#pragma unroll
  for (int i = 0; i < 4; ++i)
#pragma unroll
    for (int j = 0; j < 4; ++j) acc[i][j] = zero4();

  for (int k0 = 0; k0 < DIM; k0 += 64) {
#pragma unroll
    for (int j = 0; j < 4; ++j) {
      const int rowX = (w * 4 + j) * 8 + (lane >> 3);
      const int kcol = k0 + (lane & 7) * 8;
      GLD_LDS16(&ao[(size_t)(m0 + rowX) * DIM + kcol], &As[(w * 4 + j) * 512]);
      GLD_LDS16(&wpt[(size_t)(n0 + rowX) * DIM + kcol], &Bs[(w * 4 + j) * 512]);
    }
    asm volatile("s_waitcnt vmcnt(0)" ::: "memory");
    __syncthreads();
#pragma unroll
    for (int kc = 0; kc < 2; ++kc) {
      short8 af[4], bfr[4];
#pragma unroll
      for (int mb = 0; mb < 4; ++mb)
        af[mb] = *(const short8*)&As[(wm + mb * 16 + l15) * 64 + kc * 32 + l4 * 8];
#pragma unroll
      for (int nb = 0; nb < 4; ++nb)
        bfr[nb] = *(const short8*)&Bs[(wn + nb * 16 + l15) * 64 + kc * 32 + l4 * 8];
#pragma unroll
      for (int mb = 0; mb < 4; ++mb)
#pragma unroll
        for (int nb = 0; nb < 4; ++nb)
          acc[mb][nb] = __builtin_amdgcn_mfma_f32_16x16x32_bf16(
              af[mb], bfr[nb], acc[mb][nb], 0, 0, 0);
    }
    __syncthreads();
  }
#pragma unroll
  for (int nb = 0; nb < 4; ++nb) {
    const int col = n0 + wn + nb * 16 + l15;
    const float bv = bias[col];
#pragma unroll
    for (int mb = 0; mb < 4; ++mb)
#pragma unroll
      for (int r = 0; r < 4; ++r) {
        const int row = m0 + wm + mb * 16 + l4 * 4 + r;
        out[(size_t)row * DIM + col] = acc[mb][nb][r] + bv;
      }
  }
}

// ---------------------------------------------------------------------------
extern "C" void kernel_launch(void* const* d_in, const int* in_sizes, int n_in,
                              void* d_out, int out_size, void* d_ws, size_t ws_size,
                              hipStream_t stream) {
  const float* x      = (const float*)d_in[0];
  const float* w_qkv  = (const float*)d_in[1];
  const float* b_qkv  = (const float*)d_in[2];
  const float* w_proj = (const float*)d_in[3];
  const float* b_proj = (const float*)d_in[4];
  float* out = (float*)d_out;

  u16* ws = (u16*)d_ws;
  u16* x_bf    = ws;                               // 4096*1024
  u16* wqkv_t  = x_bf   + (size_t)MTOT * DIM;      // 3072*1024
  u16* wproj_t = wqkv_t + (size_t)3 * DIM * DIM;   // 1024*1024
  u16* qbuf    = wproj_t + (size_t)DIM * DIM;      // 32*2048*64
  u16* kbuf    = qbuf + (size_t)MTOT * DIM;
  u16* vbuf    = kbuf + (size_t)MTOT * DIM;
  u16* vtbuf   = vbuf + (size_t)MTOT * DIM;
  u16* aobuf   = vtbuf + (size_t)MTOT * DIM;

  cast_bf16_kernel<<<2048, 256, 0, stream>>>(x, x_bf, MTOT * DIM / 8);
  transpose_cast_kernel<<<dim3(96, 32), 256, 0, stream>>>(w_qkv, wqkv_t, DIM, 3 * DIM);
  transpose_cast_kernel<<<dim3(32, 32), 256, 0, stream>>>(w_proj, wproj_t, DIM, DIM);
  gemm_qkv_bf16<<<dim3(32, 24), 256, 0, stream>>>(x_bf, wqkv_t, b_qkv, qbuf, kbuf, vbuf);
  vtrans_kernel<<<dim3(32, 32), 256, 0, stream>>>(vbuf, vtbuf);
  attn_mfma<<<dim3(32, 32), 256, 0, stream>>>(qbuf, kbuf, vtbuf, aobuf);
  gemm_proj_bf16<<<dim3(32, 8), 256, 0, stream>>>(aobuf, wproj_t, b_proj, out);
}